// Round 6
// baseline (30.897 us; speedup 1.0000x reference)
//
#include <hip/hip_runtime.h>

#define IN_DIM 2048
#define OUT_DIM 2048

typedef __attribute__((ext_vector_type(4))) int int4v;

// Forced-issue 16B load: saddr form, 32-bit voffset. asm volatile keeps all
// 20 loads in one issue batch -- the compiler cannot sink/serialize them.
#define GLOAD(dst, ptr, voff)                                   \
    asm volatile("global_load_dwordx4 %0, %1, %2"               \
                 : "=v"(dst)                                    \
                 : "v"(voff), "s"(ptr)                          \
                 : "memory")

__global__ __launch_bounds__(256, 4) void ulc_kernel(
    const float* __restrict__ input_r, const float* __restrict__ input_i,
    const float* __restrict__ src_r,   const float* __restrict__ src_i,
    const float* __restrict__ rng,
    const int* __restrict__ i1_frwr, const int* __restrict__ i0_frwr,
    const int* __restrict__ i1_frwi, const int* __restrict__ i0_frwi,
    const int* __restrict__ i1_fiwr, const int* __restrict__ i0_fiwr,
    const int* __restrict__ i1_fiwi, const int* __restrict__ i0_fiwi,
    float* __restrict__ out)
{
    __shared__ float rng_s[256];
    __shared__ int redA[4], redB[4];
    const int tid = threadIdx.x;
    const int o = blockIdx.x;

    // ---- prologue: ALL compiler-tracked vmem issued and consumed here ----
    const float rv = rng[tid];
    const float4 xrA = *(const float4*)(input_r + tid * 4);
    const float4 xiA = *(const float4*)(input_i + tid * 4);
    const float4 xrB = *(const float4*)(input_r + 1024 + tid * 4);
    const float4 xiB = *(const float4*)(input_i + 1024 + tid * 4);
    rng_s[tid] = rv;                     // compiler drains rng load here

    const bool xr[8] = { xrA.x > 0.5f, xrA.y > 0.5f, xrA.z > 0.5f, xrA.w > 0.5f,
                         xrB.x > 0.5f, xrB.y > 0.5f, xrB.z > 0.5f, xrB.w > 0.5f };
    const bool xi[8] = { xiA.x > 0.5f, xiA.y > 0.5f, xiA.z > 0.5f, xiA.w > 0.5f,
                         xiB.x > 0.5f, xiB.y > 0.5f, xiB.z > 0.5f, xiB.w > 0.5f };
    __builtin_amdgcn_sched_barrier(0);

    const unsigned v0 = (unsigned)o * 8192u + (unsigned)tid * 16u;  // row*2048*4 + col*4
    const unsigned v1 = v0 + 4096u;                                 // +1024 cols

    int4v sr0, si0, a1_0, a0_0, b1_0, b0_0, c1_0, c0_0, d1_0, d0_0;
    int4v sr1, si1, a1_1, a0_1, b1_1, b0_1, c1_1, c0_1, d1_1, d0_1;

    // ---- issue all 20 loads back-to-back (1.28 KB/wave in flight) ----
    GLOAD(sr0, src_r,   v0);  GLOAD(si0, src_i,   v0);
    GLOAD(a1_0, i1_frwr, v0); GLOAD(a0_0, i0_frwr, v0);
    GLOAD(b1_0, i1_frwi, v0); GLOAD(b0_0, i0_frwi, v0);
    GLOAD(c1_0, i1_fiwr, v0); GLOAD(c0_0, i0_fiwr, v0);
    GLOAD(d1_0, i1_fiwi, v0); GLOAD(d0_0, i0_fiwi, v0);
    GLOAD(sr1, src_r,   v1);  GLOAD(si1, src_i,   v1);
    GLOAD(a1_1, i1_frwr, v1); GLOAD(a0_1, i0_frwr, v1);
    GLOAD(b1_1, i1_frwi, v1); GLOAD(b0_1, i0_frwi, v1);
    GLOAD(c1_1, i1_fiwr, v1); GLOAD(c0_1, i0_fiwr, v1);
    GLOAD(d1_1, i1_fiwi, v1); GLOAD(d0_1, i0_fiwi, v1);

    // rng_s visibility barrier UNDER the loads: raw s_barrier does NOT drain vmcnt
    asm volatile("s_waitcnt lgkmcnt(0)" ::: "memory");
    __builtin_amdgcn_s_barrier();

    int accA = 0, accB = 0;

    // bit = (src > rng[x ? idx1 : idx0]) == x ; fiwi uses x = 1-xi
    #define ELEM(k, q, xq)                                                   \
    {                                                                        \
        const float sr = __int_as_float(sr##k[q]);                           \
        const float si = __int_as_float(si##k[q]);                           \
        const bool xr_ = xr[xq], xi_ = xi[xq];                               \
        const int ia = (xr_ ? a1_##k[q] : a0_##k[q]) & 255;                  \
        const int ib = (xr_ ? b1_##k[q] : b0_##k[q]) & 255;                  \
        const int ic = (xi_ ? c1_##k[q] : c0_##k[q]) & 255;                  \
        const int id = (xi_ ? d0_##k[q] : d1_##k[q]) & 255;                  \
        const bool cA = sr > rng_s[ia];                                      \
        const bool cB = si > rng_s[ib];                                      \
        const bool cC = sr > rng_s[ic];                                      \
        const bool cD = si > rng_s[id];                                      \
        accA += (int)(cA == xr_) + (int)(cD != xi_);                         \
        accB += (int)(cB == xr_) + (int)(cC == xi_);                         \
    }

    asm volatile("s_waitcnt vmcnt(10)" ::: "memory");  // drain batch 0 only
    __builtin_amdgcn_sched_barrier(0);
    ELEM(0, 0, 0) ELEM(0, 1, 1) ELEM(0, 2, 2) ELEM(0, 3, 3)

    asm volatile("s_waitcnt vmcnt(0)" ::: "memory");   // drain batch 1
    __builtin_amdgcn_sched_barrier(0);
    ELEM(1, 0, 4) ELEM(1, 1, 5) ELEM(1, 2, 6) ELEM(1, 3, 7)
    #undef ELEM

    // ---- wave (64-lane) reduction, then cross-wave via LDS ----
    #pragma unroll
    for (int off = 32; off > 0; off >>= 1) {
        accA += __shfl_down(accA, off);
        accB += __shfl_down(accB, off);
    }
    const int wid = tid >> 6;
    if ((tid & 63) == 0) { redA[wid] = accA; redB[wid] = accB; }
    __syncthreads();
    if (tid == 0) {
        const int sA = redA[0] + redA[1] + redA[2] + redA[3];
        const int sB = redB[0] + redB[1] + redB[2] + redB[3];
        out[o]           = (sA >= 2048) ? 1.0f : 0.0f;   // acc - 2047.5 > 0
        out[OUT_DIM + o] = (sB >= 2048) ? 1.0f : 0.0f;
    }
}

extern "C" void kernel_launch(void* const* d_in, const int* in_sizes, int n_in,
                              void* d_out, int out_size, void* d_ws, size_t ws_size,
                              hipStream_t stream) {
    const float* input_r = (const float*)d_in[0];
    const float* input_i = (const float*)d_in[1];
    const float* src_r   = (const float*)d_in[2];
    const float* src_i   = (const float*)d_in[3];
    const float* rng     = (const float*)d_in[4];
    const int* i1_frwr = (const int*)d_in[5];
    const int* i0_frwr = (const int*)d_in[6];
    const int* i1_frwi = (const int*)d_in[7];
    const int* i0_frwi = (const int*)d_in[8];
    const int* i1_fiwr = (const int*)d_in[9];
    const int* i0_fiwr = (const int*)d_in[10];
    const int* i1_fiwi = (const int*)d_in[11];
    const int* i0_fiwi = (const int*)d_in[12];
    float* out = (float*)d_out;

    ulc_kernel<<<dim3(OUT_DIM), dim3(256), 0, stream>>>(
        input_r, input_i, src_r, src_i, rng,
        i1_frwr, i0_frwr, i1_frwi, i0_frwi,
        i1_fiwr, i0_fiwr, i1_fiwi, i0_fiwi,
        out);
}

// Round 7
// 29.967 us; speedup vs baseline: 1.0310x; 1.0310x over previous
//
#include <hip/hip_runtime.h>

#define IN_DIM 2048
#define OUT_DIM 2048

typedef __attribute__((ext_vector_type(4))) int int4v;

// Forced-issue 16B load: saddr form, 32-bit voffset. asm volatile pins issue
// order -- the compiler cannot sink/serialize these.
#define GLOAD(dst, ptr, voff)                                   \
    asm volatile("global_load_dwordx4 %0, %1, %2"               \
                 : "=v"(dst)                                    \
                 : "v"(voff), "s"(ptr)                          \
                 : "memory")

// Block = 4 waves. Waves 0,1 -> row 2b (halves 0,1); waves 2,3 -> row 2b+1.
// Each wave: 1024 cols = 4 batches x (10 x dwordx4), 2-deep vmcnt(10) ladder,
// no barriers in steady state.
__global__ __launch_bounds__(256, 4) void ulc_kernel(
    const float* __restrict__ input_r, const float* __restrict__ input_i,
    const float* __restrict__ src_r,   const float* __restrict__ src_i,
    const float* __restrict__ rng,
    const int* __restrict__ i1_frwr, const int* __restrict__ i0_frwr,
    const int* __restrict__ i1_frwi, const int* __restrict__ i0_frwi,
    const int* __restrict__ i1_fiwr, const int* __restrict__ i0_fiwr,
    const int* __restrict__ i1_fiwi, const int* __restrict__ i0_fiwi,
    float* __restrict__ out)
{
    __shared__ float rng_s[256];
    __shared__ int redA[4], redB[4];
    const int tid  = threadIdx.x;
    const int wid  = tid >> 6;
    const int lane = tid & 63;
    const int rowA = blockIdx.x * 2;
    const int row  = rowA + (wid >> 1);
    const int half = wid & 1;

    // ---- prologue: rng + x-vector loads, consumed immediately ----
    const float rv = rng[tid];
    const int cbase = half * 1024 + lane * 4;   // this lane's first column
    const float4 xr0 = *(const float4*)(input_r + cbase);
    const float4 xr1 = *(const float4*)(input_r + cbase + 256);
    const float4 xr2 = *(const float4*)(input_r + cbase + 512);
    const float4 xr3 = *(const float4*)(input_r + cbase + 768);
    const float4 xi0 = *(const float4*)(input_i + cbase);
    const float4 xi1 = *(const float4*)(input_i + cbase + 256);
    const float4 xi2 = *(const float4*)(input_i + cbase + 512);
    const float4 xi3 = *(const float4*)(input_i + cbase + 768);
    rng_s[tid] = rv;

    unsigned xrm = 0, xim = 0;     // 16 bits each: bit k*4+j = col (k*256 + j)
    #define PACKB(k, xv, yv)                                                  \
        xrm |= (((xv.x > 0.5f) ? 1u : 0u) << ((k)*4))                         \
             | (((xv.y > 0.5f) ? 1u : 0u) << ((k)*4+1))                       \
             | (((xv.z > 0.5f) ? 1u : 0u) << ((k)*4+2))                       \
             | (((xv.w > 0.5f) ? 1u : 0u) << ((k)*4+3));                      \
        xim |= (((yv.x > 0.5f) ? 1u : 0u) << ((k)*4))                         \
             | (((yv.y > 0.5f) ? 1u : 0u) << ((k)*4+1))                       \
             | (((yv.z > 0.5f) ? 1u : 0u) << ((k)*4+2))                       \
             | (((yv.w > 0.5f) ? 1u : 0u) << ((k)*4+3));
    PACKB(0, xr0, xi0) PACKB(1, xr1, xi1) PACKB(2, xr2, xi2) PACKB(3, xr3, xi3)
    #undef PACKB
    __builtin_amdgcn_sched_barrier(0);

    // byte offset of (row, cbase): (row*2048 + col)*4
    const unsigned v0 = (unsigned)row * 8192u + (unsigned)half * 4096u
                      + (unsigned)lane * 16u;

    int4v srP, siP, a1P, a0P, b1P, b0P, c1P, c0P, d1P, d0P;
    int4v srQ, siQ, a1Q, a0Q, b1Q, b0Q, c1Q, c0Q, d1Q, d0Q;

    #define ISSUE(S, off)                                                     \
        GLOAD(sr##S, src_r,   v0 + (off)); GLOAD(si##S, src_i,   v0 + (off)); \
        GLOAD(a1##S, i1_frwr, v0 + (off)); GLOAD(a0##S, i0_frwr, v0 + (off)); \
        GLOAD(b1##S, i1_frwi, v0 + (off)); GLOAD(b0##S, i0_frwi, v0 + (off)); \
        GLOAD(c1##S, i1_fiwr, v0 + (off)); GLOAD(c0##S, i0_fiwr, v0 + (off)); \
        GLOAD(d1##S, i1_fiwi, v0 + (off)); GLOAD(d0##S, i0_fiwi, v0 + (off));

    ISSUE(P, 0u)          // batch 0 in flight
    ISSUE(Q, 1024u)       // batch 1 in flight (20 outstanding)

    // rng_s visibility: raw s_barrier does NOT drain vmcnt -- loads keep flying
    asm volatile("s_waitcnt lgkmcnt(0)" ::: "memory");
    __builtin_amdgcn_s_barrier();

    int accA = 0, accB = 0;

    // bit = (src > rng[x ? idx1 : idx0]) == x ; fiwi uses x = 1-xi
    #define ELEM(S, j, bit)                                                   \
    {                                                                         \
        const bool xr_ = (xrm >> (bit)) & 1u;                                 \
        const bool xi_ = (xim >> (bit)) & 1u;                                 \
        const float sr = __int_as_float(sr##S[j]);                            \
        const float si = __int_as_float(si##S[j]);                            \
        const int ia = (xr_ ? a1##S[j] : a0##S[j]) & 255;                     \
        const int ib = (xr_ ? b1##S[j] : b0##S[j]) & 255;                     \
        const int ic = (xi_ ? c1##S[j] : c0##S[j]) & 255;                     \
        const int id = (xi_ ? d0##S[j] : d1##S[j]) & 255;                     \
        const bool cA = sr > rng_s[ia];                                       \
        const bool cB = si > rng_s[ib];                                       \
        const bool cC = sr > rng_s[ic];                                       \
        const bool cD = si > rng_s[id];                                       \
        accA += (int)(cA == xr_) + (int)(cD != xi_);                          \
        accB += (int)(cB == xr_) + (int)(cC == xi_);                          \
    }
    #define BATCH(S, base) ELEM(S,0,(base)) ELEM(S,1,(base)+1) ELEM(S,2,(base)+2) ELEM(S,3,(base)+3)

    asm volatile("s_waitcnt vmcnt(10)" ::: "memory");   // batch 0 ready
    __builtin_amdgcn_sched_barrier(0);
    BATCH(P, 0)
    ISSUE(P, 2048u)                                     // batch 2 into P regs
    asm volatile("s_waitcnt vmcnt(10)" ::: "memory");   // batch 1 ready
    __builtin_amdgcn_sched_barrier(0);
    BATCH(Q, 4)
    ISSUE(Q, 3072u)                                     // batch 3 into Q regs
    asm volatile("s_waitcnt vmcnt(10)" ::: "memory");   // batch 2 ready
    __builtin_amdgcn_sched_barrier(0);
    BATCH(P, 8)
    asm volatile("s_waitcnt vmcnt(0)" ::: "memory");    // batch 3 ready
    __builtin_amdgcn_sched_barrier(0);
    BATCH(Q, 12)
    #undef BATCH
    #undef ELEM
    #undef ISSUE

    // ---- wave reduction (wave owns a half-row) ----
    #pragma unroll
    for (int off = 32; off > 0; off >>= 1) {
        accA += __shfl_down(accA, off);
        accB += __shfl_down(accB, off);
    }
    if (lane == 0) { redA[wid] = accA; redB[wid] = accB; }
    __syncthreads();
    if (tid == 0) {
        out[rowA]               = (redA[0] + redA[1] >= 2048) ? 1.0f : 0.0f;
        out[rowA + 1]           = (redA[2] + redA[3] >= 2048) ? 1.0f : 0.0f;
        out[OUT_DIM + rowA]     = (redB[0] + redB[1] >= 2048) ? 1.0f : 0.0f;
        out[OUT_DIM + rowA + 1] = (redB[2] + redB[3] >= 2048) ? 1.0f : 0.0f;
    }
}

extern "C" void kernel_launch(void* const* d_in, const int* in_sizes, int n_in,
                              void* d_out, int out_size, void* d_ws, size_t ws_size,
                              hipStream_t stream) {
    const float* input_r = (const float*)d_in[0];
    const float* input_i = (const float*)d_in[1];
    const float* src_r   = (const float*)d_in[2];
    const float* src_i   = (const float*)d_in[3];
    const float* rng     = (const float*)d_in[4];
    const int* i1_frwr = (const int*)d_in[5];
    const int* i0_frwr = (const int*)d_in[6];
    const int* i1_frwi = (const int*)d_in[7];
    const int* i0_frwi = (const int*)d_in[8];
    const int* i1_fiwr = (const int*)d_in[9];
    const int* i0_fiwr = (const int*)d_in[10];
    const int* i1_fiwi = (const int*)d_in[11];
    const int* i0_fiwi = (const int*)d_in[12];
    float* out = (float*)d_out;

    ulc_kernel<<<dim3(OUT_DIM / 2), dim3(256), 0, stream>>>(
        input_r, input_i, src_r, src_i, rng,
        i1_frwr, i0_frwr, i1_frwi, i0_frwi,
        i1_fiwr, i0_fiwr, i1_fiwi, i0_fiwi,
        out);
}